// Round 9
// baseline (473.260 us; speedup 1.0000x reference)
//
#include <hip/hip_runtime.h>
#include <stdint.h>

// MHA block: B=4, S=2048, H=12, DK=64, DM=768
#define BB 4
#define SS 2048
#define HH 12
#define DKd 64
#define DM 768
#define MROWS (BB*SS)   // 8192

typedef __bf16 bfp;
typedef bfp bf16x8 __attribute__((ext_vector_type(8)));
typedef float f32x4 __attribute__((ext_vector_type(4)));

__device__ __forceinline__ unsigned short f2bf(float f) {
  union { float f; unsigned u; } c; c.f = f;
  unsigned u = c.u;
  u += 0x7FFFu + ((u >> 16) & 1u);   // RNE
  return (unsigned short)(u >> 16);
}

__device__ __forceinline__ f32x4 mfma16(bf16x8 a, bf16x8 b, f32x4 c) {
  return __builtin_amdgcn_mfma_f32_16x16x32_bf16(a, b, c, 0, 0, 0);
}

// ---------------------------------------------------------------- K0a: W -> W^T bf16
__global__ __launch_bounds__(256) void wt_kernel(
    const float* __restrict__ Wq, const float* __restrict__ Wk,
    const float* __restrict__ Wv, const float* __restrict__ Wo,
    unsigned short* __restrict__ wT) {
  __shared__ float t[32][33];
  int mtx = blockIdx.z;
  const float* W = mtx == 0 ? Wq : mtx == 1 ? Wk : mtx == 2 ? Wv : Wo;
  unsigned short* out = wT + (size_t)mtx * DM * DM;
  int n0 = blockIdx.x * 32, k0 = blockIdx.y * 32;
  int tx = threadIdx.x & 31, ty = threadIdx.x >> 5;  // 32 x 8
#pragma unroll
  for (int i = 0; i < 4; i++)
    t[ty + 8 * i][tx] = W[(size_t)(k0 + ty + 8 * i) * DM + n0 + tx];
  __syncthreads();
#pragma unroll
  for (int i = 0; i < 4; i++)
    out[(size_t)(n0 + ty + 8 * i) * DM + k0 + tx] = f2bf(t[tx][ty + 8 * i]);
}

// ---------------------------------------------------------------- K0b: mask -> bitpack
__global__ __launch_bounds__(256) void maskpack_kernel(
    const void* __restrict__ mask, unsigned short* __restrict__ pkm) {
  __shared__ int mode;  // 1 = 4-byte elems, 0 = 1-byte elems
  if (threadIdx.x == 0) {
    const unsigned* w = (const unsigned*)mask;
    bool word_like = true;
    for (int i = 0; i < 64; i++) {
      unsigned x = w[i];
      if (!(x == 0u || x == 1u || x == 0x3F800000u)) { word_like = false; break; }
    }
    mode = word_like ? 1 : 0;
  }
  __syncthreads();
  int md = mode;
  int lane = threadIdx.x & 63;
  size_t total = (size_t)BB * SS * SS;
  size_t stride = (size_t)gridDim.x * blockDim.x;
  for (size_t i = (size_t)blockIdx.x * blockDim.x + threadIdx.x; i < total; i += stride) {
    int v = md ? (((const unsigned*)mask)[i] != 0u)
               : (((const unsigned char*)mask)[i] != 0);
    unsigned long long bb = __ballot(v);
    if ((lane & 15) == 0)
      pkm[i >> 4] = (unsigned short)((bb >> lane) & 0xFFFFull);
  }
}

// ---------------------------------------------------------------- K1: QKV projection GEMM
// R3-proven staging (fp32 A + f2bf, uint4 B, padded LDS) + XCD swizzle.
#define Bb 128
#define LDA 40
__global__ __launch_bounds__(256) void proj_kernel(
    const float* __restrict__ Xq, const float* __restrict__ Xk, const float* __restrict__ Xv,
    const unsigned short* __restrict__ wTall,
    const float* __restrict__ bq, const float* __restrict__ bk, const float* __restrict__ bv,
    unsigned short* __restrict__ oq, unsigned short* __restrict__ ok, unsigned short* __restrict__ ov) {
  __shared__ unsigned short Al[Bb][LDA];
  __shared__ unsigned short Bl[Bb][LDA];

  // bijective XCD swizzle over 1152 = 8*144 blocks
  int lin = blockIdx.x + gridDim.x * (blockIdx.y + gridDim.y * blockIdx.z);
  int work = (lin & 7) * 144 + (lin >> 3);
  int z = work / 384, rem = work - z * 384;
  int xb_ = rem / 6, yb = rem - xb_ * 6;

  const float* X = z == 0 ? Xq : z == 1 ? Xk : Xv;
  const unsigned short* wT = wTall + (size_t)z * DM * DM;
  const float* bias = z == 0 ? bq : z == 1 ? bk : bv;
  unsigned short* out = z == 0 ? oq : z == 1 ? ok : ov;

  int m0 = xb_ * Bb, n0 = yb * Bb;
  int tid = threadIdx.x, lane = tid & 63, wid = tid >> 6;
  int wr = (wid >> 1) * 64, wc = (wid & 1) * 64;
  int l15 = lane & 15, l4 = lane >> 4;

  f32x4 zero = {0.f, 0.f, 0.f, 0.f};
  f32x4 acc[4][4];
#pragma unroll
  for (int m = 0; m < 4; m++)
#pragma unroll
    for (int n = 0; n < 4; n++) acc[m][n] = zero;

  for (int k0 = 0; k0 < DM; k0 += 32) {
#pragma unroll
    for (int it = 0; it < 4; it++) {           // A: 128x32 fp32 -> bf16
      int flat = it * 256 + tid;
      int r = flat >> 3, c4 = flat & 7;
      float4 v = *reinterpret_cast<const float4*>(&X[(size_t)(m0 + r) * DM + k0 + c4 * 4]);
      unsigned short* dst = &Al[r][c4 * 4];
      dst[0] = f2bf(v.x); dst[1] = f2bf(v.y); dst[2] = f2bf(v.z); dst[3] = f2bf(v.w);
    }
#pragma unroll
    for (int it = 0; it < 2; it++) {           // B: 128x32 bf16
      int flat = it * 256 + tid;
      int r = flat >> 2, c = flat & 3;
      *reinterpret_cast<uint4*>(&Bl[r][c * 8]) =
          *reinterpret_cast<const uint4*>(&wT[(size_t)(n0 + r) * DM + k0 + c * 8]);
    }
    __syncthreads();
    bf16x8 af[4], bfr[4];
#pragma unroll
    for (int m = 0; m < 4; m++)
      af[m] = *reinterpret_cast<const bf16x8*>(&Al[wr + m * 16 + l15][l4 * 8]);
#pragma unroll
    for (int n = 0; n < 4; n++)
      bfr[n] = *reinterpret_cast<const bf16x8*>(&Bl[wc + n * 16 + l15][l4 * 8]);
#pragma unroll
    for (int m = 0; m < 4; m++)
#pragma unroll
      for (int n = 0; n < 4; n++)
        acc[m][n] = mfma16(af[m], bfr[n], acc[m][n]);
    __syncthreads();
  }
  // epilogue: + bias, scatter to [B,H,S,64]
#pragma unroll
  for (int n = 0; n < 4; n++) {
    int col = n0 + wc + n * 16 + l15;
    float bv_ = bias[col];
    int h = col >> 6, d = col & 63;
#pragma unroll
    for (int m = 0; m < 4; m++) {
      int rowb = m0 + wr + m * 16 + l4 * 4;
#pragma unroll
      for (int j = 0; j < 4; j++) {
        int row = rowb + j;
        int b = row >> 11, s = row & 2047;
        out[((size_t)((b * HH + h) * SS + s)) * DKd + d] = f2bf(acc[m][n][j] + bv_);
      }
    }
  }
}

// ---------------------------------------------------------------- K1b: V -> V^T per head
__global__ __launch_bounds__(256) void vtrans_kernel(
    const unsigned short* __restrict__ v, unsigned short* __restrict__ vT) {
  __shared__ unsigned short t[64][65];
  int bh = blockIdx.y;
  int s0 = blockIdx.x * 64;
  const unsigned short* src = v + (size_t)bh * SS * DKd;
  unsigned short* dst = vT + (size_t)bh * DKd * SS;
  int tid = threadIdx.x;
#pragma unroll
  for (int it = 0; it < 16; it++) {
    int r = it * 4 + (tid >> 6), c = tid & 63;
    t[r][c] = src[(size_t)(s0 + r) * DKd + c];
  }
  __syncthreads();
#pragma unroll
  for (int it = 0; it < 16; it++) {
    int r = it * 4 + (tid >> 6), c = tid & 63;
    dst[(size_t)r * SS + s0 + c] = t[c][r];
  }
}

// ---------------------------------------------------------------- K2: flash attention
// R3's proven two-barrier structure. Deltas vs R3: LKP pad on pl (conflict fix),
// 8B-aligned pl reads, XCD-swizzled block index. NO double-buffer, NO prefetch.
#define QT 64
#define KT 64
#define LKV 72
#define LKP 76   // P pad: write banks {0,24,16,8} per l4 group -> 2-way only
__global__ __launch_bounds__(256) void attn_kernel(
    const unsigned short* __restrict__ q, const unsigned short* __restrict__ k,
    const unsigned short* __restrict__ vT, const unsigned short* __restrict__ pkm,
    unsigned short* __restrict__ ctx) {
  __shared__ unsigned short kl[KT][LKV];
  __shared__ unsigned short vl[DKd][LKV];
  __shared__ unsigned short pl[QT][LKP];

  int lin = blockIdx.x + blockIdx.y * gridDim.x;        // 0..1535
  int work = (lin & 7) * 192 + (lin >> 3);              // bijective: 8 XCDs x 192
  int bh = work >> 5;
  int q0 = (work & 31) * QT;
  int b = bh / HH, h = bh - b * HH;
  int tid = threadIdx.x, lane = tid & 63, w = tid >> 6;
  int l15 = lane & 15, l4 = lane >> 4;
  const unsigned short* qp = q + (size_t)bh * SS * DKd;
  const unsigned short* kp = k + (size_t)bh * SS * DKd;
  const unsigned short* vp = vT + (size_t)bh * DKd * SS;
  const unsigned short* pkb = pkm + (size_t)b * SS * (SS / 16);

  // wave w owns q rows [q0 + w*16, +16)
  bf16x8 aq[2];
#pragma unroll
  for (int ks = 0; ks < 2; ks++)
    aq[ks] = *reinterpret_cast<const bf16x8*>(
        &qp[(size_t)(q0 + w * 16 + l15) * DKd + ks * 32 + l4 * 8]);

  f32x4 zero = {0.f, 0.f, 0.f, 0.f};
  f32x4 acc[4];
  float lr[4] = {0.f, 0.f, 0.f, 0.f};
#pragma unroll
  for (int dn = 0; dn < 4; dn++) acc[dn] = zero;

  const float cs = 0.125f * 1.44269504f;  // log2(e)/sqrt(64)

  for (int kt = 0; kt < SS / KT; kt++) {
    // stage K tile [64][64] and V^T tile [64][64]
#pragma unroll
    for (int it = 0; it < 2; it++) {
      int flat = it * 256 + tid;
      int r = flat >> 3, c = flat & 7;
      *reinterpret_cast<uint4*>(&kl[r][c * 8]) =
          *reinterpret_cast<const uint4*>(&kp[(size_t)(kt * KT + r) * DKd + c * 8]);
    }
#pragma unroll
    for (int it = 0; it < 2; it++) {
      int flat = it * 256 + tid;
      int r = flat >> 3, c = flat & 7;
      *reinterpret_cast<uint4*>(&vl[r][c * 8]) =
          *reinterpret_cast<const uint4*>(&vp[(size_t)r * SS + kt * KT + c * 8]);
    }
    __syncthreads();

    // scores = q @ k^T  (C-layout: row=q=l4*4+j, col=kv=n*16+l15)
    f32x4 sf[4];
#pragma unroll
    for (int n = 0; n < 4; n++) sf[n] = zero;
#pragma unroll
    for (int ks = 0; ks < 2; ks++) {
#pragma unroll
      for (int n = 0; n < 4; n++) {
        bf16x8 bk_ = *reinterpret_cast<const bf16x8*>(&kl[n * 16 + l15][ks * 32 + l4 * 8]);
        sf[n] = mfma16(aq[ks], bk_, sf[n]);
      }
    }

    // fixed-max softmax: p = exp2(masked ? -1000 : s * cs); defer row-sum reduce
    unsigned long long pm[4];
#pragma unroll
    for (int j = 0; j < 4; j++)
      pm[j] = *reinterpret_cast<const unsigned long long*>(
          &pkb[(size_t)(q0 + w * 16 + l4 * 4 + j) * (SS / 16) + kt * 4]);
#pragma unroll
    for (int n = 0; n < 4; n++) {
#pragma unroll
      for (int j = 0; j < 4; j++) {
        unsigned bit = (unsigned)(pm[j] >> (n * 16 + l15)) & 1u;
        float arg = bit ? -1000.0f : sf[n][j] * cs;
        float p = __builtin_amdgcn_exp2f(arg);
        sf[n][j] = p;
        lr[j] += p;
      }
    }

    // P -> LDS (bf16 via packed cvt); rows are wave-private -> no barrier
#pragma unroll
    for (int n = 0; n < 4; n++) {
      unsigned r01, r23;
      asm("v_cvt_pk_bf16_f32 %0, %1, %2" : "=v"(r01) : "v"(sf[n][0]), "v"(sf[n][1]));
      asm("v_cvt_pk_bf16_f32 %0, %1, %2" : "=v"(r23) : "v"(sf[n][2]), "v"(sf[n][3]));
      int col = n * 16 + l15;
      pl[w * 16 + l4 * 4 + 0][col] = (unsigned short)(r01 & 0xFFFFu);
      pl[w * 16 + l4 * 4 + 1][col] = (unsigned short)(r01 >> 16);
      pl[w * 16 + l4 * 4 + 2][col] = (unsigned short)(r23 & 0xFFFFu);
      pl[w * 16 + l4 * 4 + 3][col] = (unsigned short)(r23 >> 16);
    }

    // A-frags of P (rows 8B-aligned under LKP=76 -> two b64 reads each)
    union { uint4 u; bf16x8 v; } ap[2];
#pragma unroll
    for (int ks = 0; ks < 2; ks++) {
      uint2 lo = *reinterpret_cast<const uint2*>(&pl[w * 16 + l15][ks * 32 + l4 * 8]);
      uint2 hi = *reinterpret_cast<const uint2*>(&pl[w * 16 + l15][ks * 32 + l4 * 8 + 4]);
      ap[ks].u = make_uint4(lo.x, lo.y, hi.x, hi.y);
    }

    // ctx += P @ V
#pragma unroll
    for (int ks = 0; ks < 2; ks++) {
#pragma unroll
      for (int dn = 0; dn < 4; dn++) {
        bf16x8 bv_ = *reinterpret_cast<const bf16x8*>(&vl[dn * 16 + l15][ks * 32 + l4 * 8]);
        acc[dn] = mfma16(ap[ks].v, bv_, acc[dn]);
      }
    }
    __syncthreads();
  }

  // epilogue: one row-sum reduce (across l15), then normalize + store
#pragma unroll
  for (int j = 0; j < 4; j++) {
#pragma unroll
    for (int off = 1; off < 16; off <<= 1) lr[j] += __shfl_xor(lr[j], off);
    lr[j] = 1.0f / lr[j];
  }
#pragma unroll
  for (int dn = 0; dn < 4; dn++) {
#pragma unroll
    for (int j = 0; j < 4; j++) {
      int grow = b * SS + q0 + w * 16 + l4 * 4 + j;
      ctx[(size_t)grow * DM + h * 64 + dn * 16 + l15] = f2bf(acc[dn][j] * lr[j]);
    }
  }
}

// ---------------------------------------------------------------- K3: out proj + residual
__global__ __launch_bounds__(256) void oproj_kernel(
    const unsigned short* __restrict__ ctx, const unsigned short* __restrict__ wT,
    const float* __restrict__ bo, const float* __restrict__ Qin, float* __restrict__ out) {
  __shared__ unsigned short Al[Bb][LDA];
  __shared__ unsigned short Bl[Bb][LDA];

  int lin = blockIdx.x + blockIdx.y * gridDim.x;        // 0..383, bijective 8*48
  int work = (lin & 7) * 48 + (lin >> 3);
  int xb_ = work / 6, yb = work - xb_ * 6;
  int m0 = xb_ * Bb, n0 = yb * Bb;
  int tid = threadIdx.x, lane = tid & 63, wid = tid >> 6;
  int wr = (wid >> 1) * 64, wc = (wid & 1) * 64;
  int l15 = lane & 15, l4 = lane >> 4;

  f32x4 zero = {0.f, 0.f, 0.f, 0.f};
  f32x4 acc[4][4];
#pragma unroll
  for (int m = 0; m < 4; m++)
#pragma unroll
    for (int n = 0; n < 4; n++) acc[m][n] = zero;

  for (int k0 = 0; k0 < DM; k0 += 32) {
#pragma unroll
    for (int it = 0; it < 2; it++) {
      int flat = it * 256 + tid;
      int r = flat >> 2, c = flat & 3;
      *reinterpret_cast<uint4*>(&Al[r][c * 8]) =
          *reinterpret_cast<const uint4*>(&ctx[(size_t)(m0 + r) * DM + k0 + c * 8]);
    }
#pragma unroll
    for (int it = 0; it < 2; it++) {
      int flat = it * 256 + tid;
      int r = flat >> 2, c = flat & 3;
      *reinterpret_cast<uint4*>(&Bl[r][c * 8]) =
          *reinterpret_cast<const uint4*>(&wT[(size_t)(n0 + r) * DM + k0 + c * 8]);
    }
    __syncthreads();
    bf16x8 af[4], bfr[4];
#pragma unroll
    for (int m = 0; m < 4; m++)
      af[m] = *reinterpret_cast<const bf16x8*>(&Al[wr + m * 16 + l15][l4 * 8]);
#pragma unroll
    for (int n = 0; n < 4; n++)
      bfr[n] = *reinterpret_cast<const bf16x8*>(&Bl[wc + n * 16 + l15][l4 * 8]);
#pragma unroll
    for (int m = 0; m < 4; m++)
#pragma unroll
      for (int n = 0; n < 4; n++)
        acc[m][n] = mfma16(af[m], bfr[n], acc[m][n]);
    __syncthreads();
  }
#pragma unroll
  for (int n = 0; n < 4; n++) {
    int col = n0 + wc + n * 16 + l15;
    float bv_ = bo[col];
#pragma unroll
    for (int m = 0; m < 4; m++) {
      int rowb = m0 + wr + m * 16 + l4 * 4;
#pragma unroll
      for (int j = 0; j < 4; j++) {
        int row = rowb + j;
        out[(size_t)row * DM + col] = acc[m][n][j] + bv_ + Qin[(size_t)row * DM + col];
      }
    }
  }
}

// ---------------------------------------------------------------- K4: LayerNorm in-place
__global__ __launch_bounds__(256) void ln_kernel(
    float* __restrict__ out, const float* __restrict__ gamma, const float* __restrict__ beta) {
  int row = blockIdx.x;
  float* p = out + (size_t)row * DM;
  int t = threadIdx.x;
  float x0 = p[t], x1 = p[t + 256], x2 = p[t + 512];
  float s = x0 + x1 + x2, s2 = x0 * x0 + x1 * x1 + x2 * x2;
#pragma unroll
  for (int off = 1; off < 64; off <<= 1) {
    s += __shfl_xor(s, off);
    s2 += __shfl_xor(s2, off);
  }
  __shared__ float red[8];
  int w = t >> 6, lane = t & 63;
  if (lane == 0) { red[w] = s; red[4 + w] = s2; }
  __syncthreads();
  s = red[0] + red[1] + red[2] + red[3];
  s2 = red[4] + red[5] + red[6] + red[7];
  float mu = s * (1.0f / DM);
  float var = s2 * (1.0f / DM) - mu * mu;
  float rs = rsqrtf(var + 1e-5f);
  p[t] = (x0 - mu) * rs * gamma[t] + beta[t];
  p[t + 256] = (x1 - mu) * rs * gamma[t + 256] + beta[t + 256];
  p[t + 512] = (x2 - mu) * rs * gamma[t + 512] + beta[t + 512];
}

// ---------------------------------------------------------------- launch
extern "C" void kernel_launch(void* const* d_in, const int* in_sizes, int n_in,
                              void* d_out, int out_size, void* d_ws, size_t ws_size,
                              hipStream_t stream) {
  const float* Qin = (const float*)d_in[0];
  const float* Kin = (const float*)d_in[1];
  const float* Vin = (const float*)d_in[2];
  const void* mask = d_in[3];
  const float* Wq = (const float*)d_in[4];
  const float* bq = (const float*)d_in[5];
  const float* Wk = (const float*)d_in[6];
  const float* bk = (const float*)d_in[7];
  const float* Wv = (const float*)d_in[8];
  const float* bv = (const float*)d_in[9];
  const float* Wo = (const float*)d_in[10];
  const float* bo = (const float*)d_in[11];
  const float* gamma = (const float*)d_in[12];
  const float* beta = (const float*)d_in[13];

  char* ws = (char*)d_ws;
  // R3-proven layout (57.1 MB): wT 4.72MB | pk 2.10MB | q,k,v,vT bf16 12.58MB each
  unsigned short* wT  = (unsigned short*)(ws);
  unsigned short* pk  = (unsigned short*)(ws + 4718592);
  unsigned short* qb  = (unsigned short*)(ws + 6815744);
  unsigned short* kb  = (unsigned short*)(ws + 6815744 + 12582912);
  unsigned short* vb  = (unsigned short*)(ws + 6815744 + 2 * 12582912);
  unsigned short* vTb = (unsigned short*)(ws + 6815744 + 3 * 12582912);
  unsigned short* ctx = vb;  // v no longer needed once vT exists

  wt_kernel<<<dim3(24, 24, 4), 256, 0, stream>>>(Wq, Wk, Wv, Wo, wT);
  maskpack_kernel<<<2048, 256, 0, stream>>>(mask, pk);
  proj_kernel<<<dim3(64, 6, 3), 256, 0, stream>>>(Qin, Kin, Vin, wT, bq, bk, bv, qb, kb, vb);
  vtrans_kernel<<<dim3(32, 48), 256, 0, stream>>>(vb, vTb);
  attn_kernel<<<dim3(32, 48), 256, 0, stream>>>(qb, kb, vTb, pk, ctx);
  oproj_kernel<<<dim3(64, 6), 256, 0, stream>>>(ctx, wT + (size_t)3 * DM * DM, bo, Qin, (float*)d_out);
  ln_kernel<<<8192, 256, 0, stream>>>((float*)d_out, gamma, beta);
}

// Round 10
// 443.094 us; speedup vs baseline: 1.0681x; 1.0681x over previous
//
#include <hip/hip_runtime.h>
#include <stdint.h>

// MHA block: B=4, S=2048, H=12, DK=64, DM=768
#define BB 4
#define SS 2048
#define HH 12
#define DKd 64
#define DM 768
#define MROWS (BB*SS)   // 8192

typedef __bf16 bfp;
typedef bfp bf16x8 __attribute__((ext_vector_type(8)));
typedef float f32x4 __attribute__((ext_vector_type(4)));

__device__ __forceinline__ unsigned short f2bf(float f) {
  union { float f; unsigned u; } c; c.f = f;
  unsigned u = c.u;
  u += 0x7FFFu + ((u >> 16) & 1u);   // RNE
  return (unsigned short)(u >> 16);
}

__device__ __forceinline__ f32x4 mfma16(bf16x8 a, bf16x8 b, f32x4 c) {
  return __builtin_amdgcn_mfma_f32_16x16x32_bf16(a, b, c, 0, 0, 0);
}

__device__ __forceinline__ void gload_lds16(const void* g, void* l) {
  __builtin_amdgcn_global_load_lds(
      (const __attribute__((address_space(1))) unsigned int*)g,
      (__attribute__((address_space(3))) unsigned int*)l, 16, 0, 0);
}

// ---------------------------------------------------------------- K0a: W -> W^T bf16
__global__ __launch_bounds__(256) void wt_kernel(
    const float* __restrict__ Wq, const float* __restrict__ Wk,
    const float* __restrict__ Wv, const float* __restrict__ Wo,
    unsigned short* __restrict__ wT) {
  __shared__ float t[32][33];
  int mtx = blockIdx.z;
  const float* W = mtx == 0 ? Wq : mtx == 1 ? Wk : mtx == 2 ? Wv : Wo;
  unsigned short* out = wT + (size_t)mtx * DM * DM;
  int n0 = blockIdx.x * 32, k0 = blockIdx.y * 32;
  int tx = threadIdx.x & 31, ty = threadIdx.x >> 5;  // 32 x 8
#pragma unroll
  for (int i = 0; i < 4; i++)
    t[ty + 8 * i][tx] = W[(size_t)(k0 + ty + 8 * i) * DM + n0 + tx];
  __syncthreads();
#pragma unroll
  for (int i = 0; i < 4; i++)
    out[(size_t)(n0 + ty + 8 * i) * DM + k0 + tx] = f2bf(t[tx][ty + 8 * i]);
}

// ---------------------------------------------------------------- K0b: mask -> bitpack
__global__ __launch_bounds__(256) void maskpack_kernel(
    const void* __restrict__ mask, unsigned short* __restrict__ pkm) {
  __shared__ int mode;  // 1 = 4-byte elems, 0 = 1-byte elems
  if (threadIdx.x == 0) {
    const unsigned* w = (const unsigned*)mask;
    bool word_like = true;
    for (int i = 0; i < 64; i++) {
      unsigned x = w[i];
      if (!(x == 0u || x == 1u || x == 0x3F800000u)) { word_like = false; break; }
    }
    mode = word_like ? 1 : 0;
  }
  __syncthreads();
  int md = mode;
  int lane = threadIdx.x & 63;
  size_t total = (size_t)BB * SS * SS;
  size_t stride = (size_t)gridDim.x * blockDim.x;
  for (size_t i = (size_t)blockIdx.x * blockDim.x + threadIdx.x; i < total; i += stride) {
    int v = md ? (((const unsigned*)mask)[i] != 0u)
               : (((const unsigned char*)mask)[i] != 0);
    unsigned long long bb = __ballot(v);
    if ((lane & 15) == 0)
      pkm[i >> 4] = (unsigned short)((bb >> lane) & 0xFFFFull);
  }
}

// ---------------------------------------------------------------- K0c: X fp32 -> bf16
__global__ __launch_bounds__(256) void cvt_kernel(
    const float* __restrict__ Q, const float* __restrict__ K, const float* __restrict__ V,
    unsigned short* __restrict__ xb) {
  int z = blockIdx.z;
  const float* src = z == 0 ? Q : z == 1 ? K : V;
  unsigned short* dst = xb + (size_t)z * MROWS * DM;
  size_t i = ((size_t)blockIdx.x * 256 + threadIdx.x) * 4;
  float4 v = *reinterpret_cast<const float4*>(&src[i]);
  unsigned r01, r23;
  asm("v_cvt_pk_bf16_f32 %0, %1, %2" : "=v"(r01) : "v"(v.x), "v"(v.y));
  asm("v_cvt_pk_bf16_f32 %0, %1, %2" : "=v"(r23) : "v"(v.z), "v"(v.w));
  *reinterpret_cast<uint2*>(&dst[i]) = make_uint2(r01, r23);
}

// ---------------------------------------------------------------- K1: QKV projection GEMM
// Xb[3][8192][768] bf16 @ wT -> [B,H,S,64] bf16.  m97-style global_load_lds staging.
#define Bb 128
#define BKp 32
__global__ __launch_bounds__(256) void proj_kernel(
    const unsigned short* __restrict__ Xall, const unsigned short* __restrict__ wTall,
    const float* __restrict__ bq, const float* __restrict__ bk, const float* __restrict__ bv,
    unsigned short* __restrict__ oq, unsigned short* __restrict__ ok, unsigned short* __restrict__ ov) {
  __shared__ unsigned short Al[Bb][BKp];
  __shared__ unsigned short Bl[Bb][BKp];

  // bijective XCD swizzle over 1152 = 8*144 blocks
  int lin = blockIdx.x + gridDim.x * (blockIdx.y + gridDim.y * blockIdx.z);
  int work = (lin & 7) * 144 + (lin >> 3);
  int z = work / 384, rem = work - z * 384;
  int xb_ = rem / 6, yb = rem - xb_ * 6;

  const unsigned short* X = Xall + (size_t)z * MROWS * DM;
  const unsigned short* wT = wTall + (size_t)z * DM * DM;
  const float* bias = z == 0 ? bq : z == 1 ? bk : bv;
  unsigned short* out = z == 0 ? oq : z == 1 ? ok : ov;

  int m0 = xb_ * Bb, n0 = yb * Bb;
  int tid = threadIdx.x, lane = tid & 63, wid = tid >> 6;
  int wr = (wid >> 1) * 64, wc = (wid & 1) * 64;
  int l15 = lane & 15, l4 = lane >> 4;

  f32x4 zero = {0.f, 0.f, 0.f, 0.f};
  f32x4 acc[4][4];
#pragma unroll
  for (int m = 0; m < 4; m++)
#pragma unroll
    for (int n = 0; n < 4; n++) acc[m][n] = zero;

  for (int k0 = 0; k0 < DM; k0 += BKp) {
#pragma unroll
    for (int r = 0; r < 2; ++r) {
      int seg = r * 4 + wid;                 // 0..7, 1 KB each
      int Lb = seg * 1024 + lane * 16;       // byte within [128][32]-bf16 tile
      int row = Lb >> 6;
      int cu = (Lb & 63) >> 1;
      gload_lds16(&X[(size_t)(m0 + row) * DM + k0 + cu], (char*)&Al[0][0] + seg * 1024);
      gload_lds16(&wT[(size_t)(n0 + row) * DM + k0 + cu], (char*)&Bl[0][0] + seg * 1024);
    }
    __syncthreads();
    bf16x8 af[4], bfr[4];
#pragma unroll
    for (int m = 0; m < 4; m++)
      af[m] = *reinterpret_cast<const bf16x8*>(&Al[wr + m * 16 + l15][l4 * 8]);
#pragma unroll
    for (int n = 0; n < 4; n++)
      bfr[n] = *reinterpret_cast<const bf16x8*>(&Bl[wc + n * 16 + l15][l4 * 8]);
#pragma unroll
    for (int m = 0; m < 4; m++)
#pragma unroll
      for (int n = 0; n < 4; n++)
        acc[m][n] = mfma16(af[m], bfr[n], acc[m][n]);
    __syncthreads();
  }
  // epilogue: + bias, scatter to [B,H,S,64]
#pragma unroll
  for (int n = 0; n < 4; n++) {
    int col = n0 + wc + n * 16 + l15;
    float bv_ = bias[col];
    int h = col >> 6, d = col & 63;
#pragma unroll
    for (int m = 0; m < 4; m++) {
      int rowb = m0 + wr + m * 16 + l4 * 4;
#pragma unroll
      for (int j = 0; j < 4; j++) {
        int row = rowb + j;
        int b = row >> 11, s = row & 2047;
        out[((size_t)((b * HH + h) * SS + s)) * DKd + d] = f2bf(acc[m][n][j] + bv_);
      }
    }
  }
}

// ---------------------------------------------------------------- K1b: V -> V^T per head
__global__ __launch_bounds__(256) void vtrans_kernel(
    const unsigned short* __restrict__ v, unsigned short* __restrict__ vT) {
  __shared__ unsigned short t[64][65];
  int bh = blockIdx.y;
  int s0 = blockIdx.x * 64;
  const unsigned short* src = v + (size_t)bh * SS * DKd;
  unsigned short* dst = vT + (size_t)bh * DKd * SS;
  int tid = threadIdx.x;
#pragma unroll
  for (int it = 0; it < 16; it++) {
    int r = it * 4 + (tid >> 6), c = tid & 63;
    t[r][c] = src[(size_t)(s0 + r) * DKd + c];
  }
  __syncthreads();
#pragma unroll
  for (int it = 0; it < 16; it++) {
    int r = it * 4 + (tid >> 6), c = tid & 63;
    dst[(size_t)r * SS + s0 + c] = t[c][r];
  }
}

// ---------------------------------------------------------------- K2: flash attention
// R9's proven two-barrier structure, KT scaled 64->128 (half the barriers,
// 2x ILP per interval). NO double-buffer, NO prefetch (R7/R8 lesson).
#define QT 64
#define KT 128
#define LKV 72    // kl pad: 144 B rows
#define LDV 136   // vl pad: 272 B rows
#define LKP 132   // pl pad: 264 B rows (8B-aligned)
__global__ __launch_bounds__(256) void attn_kernel(
    const unsigned short* __restrict__ q, const unsigned short* __restrict__ k,
    const unsigned short* __restrict__ vT, const unsigned short* __restrict__ pkm,
    unsigned short* __restrict__ ctx) {
  __shared__ unsigned short kl[KT][LKV];    // 18432 B
  __shared__ unsigned short vl[DKd][LDV];   // 17408 B
  __shared__ unsigned short pl[QT][LKP];    // 16896 B

  int lin = blockIdx.x + blockIdx.y * gridDim.x;        // 0..1535
  int work = (lin & 7) * 192 + (lin >> 3);              // bijective: 8 XCDs x 192
  int bh = work >> 5;
  int q0 = (work & 31) * QT;
  int b = bh / HH, h = bh - b * HH;
  int tid = threadIdx.x, lane = tid & 63, w = tid >> 6;
  int l15 = lane & 15, l4 = lane >> 4;
  const unsigned short* qp = q + (size_t)bh * SS * DKd;
  const unsigned short* kp = k + (size_t)bh * SS * DKd;
  const unsigned short* vp = vT + (size_t)bh * DKd * SS;
  const unsigned short* pkb = pkm + (size_t)b * SS * (SS / 16);

  // wave w owns q rows [q0 + w*16, +16)
  bf16x8 aq[2];
#pragma unroll
  for (int ks = 0; ks < 2; ks++)
    aq[ks] = *reinterpret_cast<const bf16x8*>(
        &qp[(size_t)(q0 + w * 16 + l15) * DKd + ks * 32 + l4 * 8]);

  f32x4 zero = {0.f, 0.f, 0.f, 0.f};
  f32x4 acc[4];
  float lr[4] = {0.f, 0.f, 0.f, 0.f};
#pragma unroll
  for (int dn = 0; dn < 4; dn++) acc[dn] = zero;

  const float cs = 0.125f * 1.44269504f;  // log2(e)/sqrt(64)

  for (int kt = 0; kt < SS / KT; kt++) {   // 16 tiles
    // stage K tile [128][64]
#pragma unroll
    for (int it = 0; it < 4; it++) {
      int flat = it * 256 + tid;
      int r = flat >> 3, c = flat & 7;
      *reinterpret_cast<uint4*>(&kl[r][c * 8]) =
          *reinterpret_cast<const uint4*>(&kp[(size_t)(kt * KT + r) * DKd + c * 8]);
    }
    // stage V^T tile [64][128]
#pragma unroll
    for (int it = 0; it < 4; it++) {
      int flat = it * 256 + tid;
      int r = flat >> 4, c = flat & 15;
      *reinterpret_cast<uint4*>(&vl[r][c * 8]) =
          *reinterpret_cast<const uint4*>(&vp[(size_t)r * SS + kt * KT + c * 8]);
    }
    __syncthreads();

    // scores = q @ k^T  (8 n-blocks of 16 kv each)
    f32x4 sf[8];
#pragma unroll
    for (int n = 0; n < 8; n++) sf[n] = zero;
#pragma unroll
    for (int ks = 0; ks < 2; ks++) {
#pragma unroll
      for (int n = 0; n < 8; n++) {
        bf16x8 bk_ = *reinterpret_cast<const bf16x8*>(&kl[n * 16 + l15][ks * 32 + l4 * 8]);
        sf[n] = mfma16(aq[ks], bk_, sf[n]);
      }
    }

    // mask: 128 bits/row = 4 u32 words
    unsigned mw[4][4];
#pragma unroll
    for (int j = 0; j < 4; j++) {
      uint4 mm = *reinterpret_cast<const uint4*>(
          &pkb[(size_t)(q0 + w * 16 + l4 * 4 + j) * (SS / 16) + kt * 8]);
      mw[j][0] = mm.x; mw[j][1] = mm.y; mw[j][2] = mm.z; mw[j][3] = mm.w;
    }

    // fixed-max softmax + P -> LDS
#pragma unroll
    for (int n = 0; n < 8; n++) {
      unsigned sh = (n & 1) * 16;
#pragma unroll
      for (int j = 0; j < 4; j++) {
        unsigned bit = (mw[j][n >> 1] >> (sh + l15)) & 1u;
        float arg = bit ? -1000.0f : sf[n][j] * cs;
        float p = __builtin_amdgcn_exp2f(arg);
        sf[n][j] = p;
        lr[j] += p;
      }
      unsigned r01, r23;
      asm("v_cvt_pk_bf16_f32 %0, %1, %2" : "=v"(r01) : "v"(sf[n][0]), "v"(sf[n][1]));
      asm("v_cvt_pk_bf16_f32 %0, %1, %2" : "=v"(r23) : "v"(sf[n][2]), "v"(sf[n][3]));
      int col = n * 16 + l15;
      pl[w * 16 + l4 * 4 + 0][col] = (unsigned short)(r01 & 0xFFFFu);
      pl[w * 16 + l4 * 4 + 1][col] = (unsigned short)(r01 >> 16);
      pl[w * 16 + l4 * 4 + 2][col] = (unsigned short)(r23 & 0xFFFFu);
      pl[w * 16 + l4 * 4 + 3][col] = (unsigned short)(r23 >> 16);
    }

    // A-frags of P (rows 8B-aligned -> two b64 reads each)
    union { uint4 u; bf16x8 v; } ap[4];
#pragma unroll
    for (int ks = 0; ks < 4; ks++) {
      uint2 lo = *reinterpret_cast<const uint2*>(&pl[w * 16 + l15][ks * 32 + l4 * 8]);
      uint2 hi = *reinterpret_cast<const uint2*>(&pl[w * 16 + l15][ks * 32 + l4 * 8 + 4]);
      ap[ks].u = make_uint4(lo.x, lo.y, hi.x, hi.y);
    }

    // ctx += P @ V   (k-dim 128 = 4 ks-blocks)
#pragma unroll
    for (int ks = 0; ks < 4; ks++) {
#pragma unroll
      for (int dn = 0; dn < 4; dn++) {
        bf16x8 bv_ = *reinterpret_cast<const bf16x8*>(&vl[dn * 16 + l15][ks * 32 + l4 * 8]);
        acc[dn] = mfma16(ap[ks].v, bv_, acc[dn]);
      }
    }
    __syncthreads();
  }

  // epilogue: one row-sum reduce (across l15), then normalize + store
#pragma unroll
  for (int j = 0; j < 4; j++) {
#pragma unroll
    for (int off = 1; off < 16; off <<= 1) lr[j] += __shfl_xor(lr[j], off);
    lr[j] = 1.0f / lr[j];
  }
#pragma unroll
  for (int dn = 0; dn < 4; dn++) {
#pragma unroll
    for (int j = 0; j < 4; j++) {
      int grow = b * SS + q0 + w * 16 + l4 * 4 + j;
      ctx[(size_t)grow * DM + h * 64 + dn * 16 + l15] = f2bf(acc[dn][j] * lr[j]);
    }
  }
}

// ---------------------------------------------------------------- K3: out proj + residual
__global__ __launch_bounds__(256) void oproj_kernel(
    const unsigned short* __restrict__ ctx, const unsigned short* __restrict__ wT,
    const float* __restrict__ bo, const float* __restrict__ Qin, float* __restrict__ out) {
  __shared__ unsigned short Al[Bb][BKp];
  __shared__ unsigned short Bl[Bb][BKp];

  int lin = blockIdx.x + blockIdx.y * gridDim.x;        // 0..383, bijective 8*48
  int work = (lin & 7) * 48 + (lin >> 3);
  int xb_ = work / 6, yb = work - xb_ * 6;
  int m0 = xb_ * Bb, n0 = yb * Bb;
  int tid = threadIdx.x, lane = tid & 63, wid = tid >> 6;
  int wr = (wid >> 1) * 64, wc = (wid & 1) * 64;
  int l15 = lane & 15, l4 = lane >> 4;

  f32x4 zero = {0.f, 0.f, 0.f, 0.f};
  f32x4 acc[4][4];
#pragma unroll
  for (int m = 0; m < 4; m++)
#pragma unroll
    for (int n = 0; n < 4; n++) acc[m][n] = zero;

  for (int k0 = 0; k0 < DM; k0 += BKp) {
#pragma unroll
    for (int r = 0; r < 2; ++r) {
      int seg = r * 4 + wid;
      int Lb = seg * 1024 + lane * 16;
      int row = Lb >> 6;
      int cu = (Lb & 63) >> 1;
      gload_lds16(&ctx[(size_t)(m0 + row) * DM + k0 + cu], (char*)&Al[0][0] + seg * 1024);
      gload_lds16(&wT[(size_t)(n0 + row) * DM + k0 + cu], (char*)&Bl[0][0] + seg * 1024);
    }
    __syncthreads();
    bf16x8 af[4], bfr[4];
#pragma unroll
    for (int m = 0; m < 4; m++)
      af[m] = *reinterpret_cast<const bf16x8*>(&Al[wr + m * 16 + l15][l4 * 8]);
#pragma unroll
    for (int n = 0; n < 4; n++)
      bfr[n] = *reinterpret_cast<const bf16x8*>(&Bl[wc + n * 16 + l15][l4 * 8]);
#pragma unroll
    for (int m = 0; m < 4; m++)
#pragma unroll
      for (int n = 0; n < 4; n++)
        acc[m][n] = mfma16(af[m], bfr[n], acc[m][n]);
    __syncthreads();
  }
#pragma unroll
  for (int n = 0; n < 4; n++) {
    int col = n0 + wc + n * 16 + l15;
    float bv_ = bo[col];
#pragma unroll
    for (int m = 0; m < 4; m++) {
      int rowb = m0 + wr + m * 16 + l4 * 4;
#pragma unroll
      for (int j = 0; j < 4; j++) {
        int row = rowb + j;
        out[(size_t)row * DM + col] = acc[m][n][j] + bv_ + Qin[(size_t)row * DM + col];
      }
    }
  }
}

// ---------------------------------------------------------------- K4: LayerNorm in-place
__global__ __launch_bounds__(256) void ln_kernel(
    float* __restrict__ out, const float* __restrict__ gamma, const float* __restrict__ beta) {
  int row = blockIdx.x;
  float* p = out + (size_t)row * DM;
  int t = threadIdx.x;
  float x0 = p[t], x1 = p[t + 256], x2 = p[t + 512];
  float s = x0 + x1 + x2, s2 = x0 * x0 + x1 * x1 + x2 * x2;
#pragma unroll
  for (int off = 1; off < 64; off <<= 1) {
    s += __shfl_xor(s, off);
    s2 += __shfl_xor(s2, off);
  }
  __shared__ float red[8];
  int w = t >> 6, lane = t & 63;
  if (lane == 0) { red[w] = s; red[4 + w] = s2; }
  __syncthreads();
  s = red[0] + red[1] + red[2] + red[3];
  s2 = red[4] + red[5] + red[6] + red[7];
  float mu = s * (1.0f / DM);
  float var = s2 * (1.0f / DM) - mu * mu;
  float rs = rsqrtf(var + 1e-5f);
  p[t] = (x0 - mu) * rs * gamma[t] + beta[t];
  p[t + 256] = (x1 - mu) * rs * gamma[t + 256] + beta[t + 256];
  p[t + 512] = (x2 - mu) * rs * gamma[t + 512] + beta[t + 512];
}

// ---------------------------------------------------------------- launch
extern "C" void kernel_launch(void* const* d_in, const int* in_sizes, int n_in,
                              void* d_out, int out_size, void* d_ws, size_t ws_size,
                              hipStream_t stream) {
  const float* Qin = (const float*)d_in[0];
  const float* Kin = (const float*)d_in[1];
  const float* Vin = (const float*)d_in[2];
  const void* mask = d_in[3];
  const float* Wq = (const float*)d_in[4];
  const float* bq = (const float*)d_in[5];
  const float* Wk = (const float*)d_in[6];
  const float* bk = (const float*)d_in[7];
  const float* Wv = (const float*)d_in[8];
  const float* bv = (const float*)d_in[9];
  const float* Wo = (const float*)d_in[10];
  const float* bo = (const float*)d_in[11];
  const float* gamma = (const float*)d_in[12];
  const float* beta = (const float*)d_in[13];

  char* ws = (char*)d_ws;
  // R7 layout (94.9 MB, validated by R7/R8 identical-absmax inference):
  // wT 4.72MB | pk 2.10MB | xb 37.75MB | qb,kb,vb 12.58MB each | vTb 12.58MB
  unsigned short* wT  = (unsigned short*)(ws);
  unsigned short* pk  = (unsigned short*)(ws + 4718592);
  unsigned short* xbf = (unsigned short*)(ws + 6815744);
  unsigned short* qb  = (unsigned short*)(ws + 6815744 + 37748736);
  unsigned short* kb  = (unsigned short*)(ws + 6815744 + 37748736 + 12582912);
  unsigned short* vb  = (unsigned short*)(ws + 6815744 + 37748736 + 2 * 12582912);
  unsigned short* vTb = (unsigned short*)(ws + 6815744 + 37748736 + 3 * 12582912);
  unsigned short* ctx = vb;  // v no longer needed once vT exists

  wt_kernel<<<dim3(24, 24, 4), 256, 0, stream>>>(Wq, Wk, Wv, Wo, wT);
  maskpack_kernel<<<2048, 256, 0, stream>>>(mask, pk);
  cvt_kernel<<<dim3(6144, 1, 3), 256, 0, stream>>>(Qin, Kin, Vin, xbf);
  proj_kernel<<<dim3(64, 6, 3), 256, 0, stream>>>(xbf, wT, bq, bk, bv, qb, kb, vb);
  vtrans_kernel<<<dim3(32, 48), 256, 0, stream>>>(vb, vTb);
  attn_kernel<<<dim3(32, 48), 256, 0, stream>>>(qb, kb, vTb, pk, ctx);
  oproj_kernel<<<dim3(64, 6), 256, 0, stream>>>(ctx, wT + (size_t)3 * DM * DM, bo, Qin, (float*)d_out);
  ln_kernel<<<8192, 256, 0, stream>>>((float*)d_out, gamma, beta);
}